// Round 17
// baseline (131.619 us; speedup 1.0000x reference)
//
#include <hip/hip_runtime.h>
#include <hip/hip_bf16.h>
#include <math.h>

#define BB 8
#define TT 2048
#define EE 1024
#define HH 64
// 1/sqrt(64) * log2(e): fold into q so scores are in exp2 domain
#define QSCALE 0.18033688011112042f
#define REPS_P 2   // measurement: surface proj in top-5
#define REPS_A 4   // measurement: surface attn in top-5

typedef __attribute__((ext_vector_type(8))) short short8;
typedef __attribute__((ext_vector_type(4))) float f32x4;
typedef __attribute__((ext_vector_type(4))) unsigned short us4;

__device__ inline unsigned short f2bf(float f) {
  union { __hip_bfloat16 h; unsigned short u; } cv;
  cv.h = __float2bfloat16(f);
  return cv.u;
}

// ---------- prep: fragment-ordered weights --------------------------------
__global__ __launch_bounds__(256) void prep_w(
    const float* __restrict__ Wk, const float* __restrict__ Wq,
    const float* __restrict__ Wv, unsigned short* __restrict__ Wf) {
  const int idx = blockIdx.x * 256 + threadIdx.x;  // 12*32*64 = 24576
  const int lane = idx & 63, ks = (idx >> 6) & 31, t = idx >> 11;
  const int q = lane & 15, g = lane >> 4;
  const int m = t >> 2, h = (t & 3) * 16 + q;
  const float* W = (m == 0) ? Wk : (m == 1) ? Wq : Wv;
  const float sc = (m == 1) ? QSCALE : 1.f;
  const int e0 = ks * 32 + g * 8;
  unsigned short v[8];
  #pragma unroll
  for (int j = 0; j < 8; ++j) v[j] = f2bf(W[(e0 + j) * 64 + h] * sc);
  *(short8*)&Wf[(size_t)idx * 8] = *(short8*)v;
}

// ---------- QKV projection v7 (x REPS_P for measurement) -------------------
__global__ __launch_bounds__(256) void qkv_proj(
    const float* __restrict__ x,
    const float* __restrict__ bk, const float* __restrict__ bq,
    const float* __restrict__ bv, const unsigned short* __restrict__ Wf,
    unsigned short* __restrict__ kf, unsigned short* __restrict__ qf,
    unsigned short* __restrict__ vf) {
  __shared__ alignas(16) unsigned short xs[16][1040];
  __shared__ alignas(16) unsigned short img[3072];

  const int tid = threadIdx.x;
  const long row0 = (long)blockIdx.x * 16;
  const int w = tid >> 6, lane = tid & 63;
  const int q = lane & 15, g = lane >> 4;

  const float4* xg = (const float4*)&x[row0 * EE];

  for (int rep = 0; rep < REPS_P; ++rep) {
    __syncthreads();
    #pragma unroll
    for (int i = 0; i < 16; ++i) {
      const int flat = i * 256 + tid;
      const int rr = flat >> 8, c4 = flat & 255;
      const float4 xv = xg[flat];
      us4 pk = {f2bf(xv.x), f2bf(xv.y), f2bf(xv.z), f2bf(xv.w)};
      *(us4*)&xs[rr][c4 * 4] = pk;
    }
    __syncthreads();

    const f32x4 z = {0.f, 0.f, 0.f, 0.f};
    f32x4 acc0 = z, acc1 = z, acc2 = z;
    const unsigned short* wf0 = &Wf[(size_t)w * 16384 + (size_t)lane * 8];

    #pragma unroll 8
    for (int ks = 0; ks < 32; ++ks) {
      const short8 af = *(const short8*)&xs[q][ks * 32 + g * 8];
      const short8 b0 = *(const short8*)&wf0[ks * 512];
      const short8 b1 = *(const short8*)&wf0[65536 + ks * 512];
      const short8 b2 = *(const short8*)&wf0[131072 + ks * 512];
      acc0 = __builtin_amdgcn_mfma_f32_16x16x32_bf16(af, b0, acc0, 0, 0, 0);
      acc1 = __builtin_amdgcn_mfma_f32_16x16x32_bf16(af, b1, acc1, 0, 0, 0);
      acc2 = __builtin_amdgcn_mfma_f32_16x16x32_bf16(af, b2, acc2, 0, 0, 0);
    }

    const int h = w * 16 + q;
    const float biask = bk[h], biasq = bq[h] * QSCALE, biasv = bv[h];
    #pragma unroll
    for (int i = 0; i < 3; ++i) {
      const f32x4 a = (i == 0) ? acc0 : (i == 1) ? acc1 : acc2;
      const float bias = (i == 0) ? biask : (i == 1) ? biasq : biasv;
      #pragma unroll
      for (int r = 0; r < 4; ++r) {
        const int tlh = 4 * g + r;
        const unsigned short ov = f2bf(a[r] + bias);
        if (i == 2) {
          img[2048 + w * 256 + (tlh >> 3) * 128 + q * 8 + (tlh & 7)] = ov;
        } else {
          const int g2 = (w & 1) * 2 + (q >> 3);
          img[i * 1024 + (w >> 1) * 512 + g2 * 128 + tlh * 8 + (q & 7)] = ov;
        }
      }
    }
    __syncthreads();

    const long bidx = row0 >> 11;
    const int tlg = (int)(row0 & 2047);
    const size_t tb16 = (size_t)bidx * 131072 + (size_t)(tlg >> 4) * 1024;
    const size_t vb32 = (size_t)bidx * 131072 + (size_t)(tlg >> 5) * 2048;
    const int ks0v = (tlg >> 4) & 1;
    if (tid < 128) {
      *(short8*)&kf[tb16 + (size_t)tid * 8] = *(const short8*)&img[tid * 8];
      const int wv = tid >> 5, uu = (tid >> 4) & 1, qv = tid & 15;
      *(short8*)&vf[vb32 + wv * 512 + (2 * ks0v + uu) * 128 + qv * 8] =
          *(const short8*)&img[2048 + tid * 8];
    } else if (tid < 256) {
      const int t2 = tid - 128;
      *(short8*)&qf[tb16 + (size_t)t2 * 8] = *(const short8*)&img[1024 + t2 * 8];
    }
  }
}

// ---------- flash attention (R8/R16 structure, x REPS_A) -------------------
#define BODY(KC0, KC1, KC2, KC3, KN0, KN1, KN2, KN3, tt, PREF) do {          \
    const unsigned short* vp_ = vfb + (size_t)(tt) * 2048;                   \
    const short8 V0 = *(const short8*)&vp_[0];                               \
    const short8 V1 = *(const short8*)&vp_[512];                             \
    const short8 V2 = *(const short8*)&vp_[1024];                            \
    const short8 V3 = *(const short8*)&vp_[1536];                            \
    if (PREF) {                                                              \
      const unsigned short* kp_ = kfb + (size_t)((tt) + stride) * 2048;      \
      KN0 = *(const short8*)&kp_[0];                                         \
      KN1 = *(const short8*)&kp_[512];                                       \
      KN2 = *(const short8*)&kp_[1024];                                      \
      KN3 = *(const short8*)&kp_[1536];                                      \
    }                                                                        \
    f32x4 sa = __builtin_amdgcn_mfma_f32_16x16x32_bf16(KC0, Qf0, z, 0,0,0);  \
    sa = __builtin_amdgcn_mfma_f32_16x16x32_bf16(KC1, Qf1, sa, 0,0,0);       \
    f32x4 sb = __builtin_amdgcn_mfma_f32_16x16x32_bf16(KC2, Qf0, z, 0,0,0);  \
    sb = __builtin_amdgcn_mfma_f32_16x16x32_bf16(KC3, Qf1, sb, 0,0,0);       \
    const int k0_ = (tt) * 32;                                               \
    if (k0_ + 31 > q0) {                                                     \
      _Pragma("unroll")                                                      \
      for (int r = 0; r < 4; ++r) {                                          \
        if (k0_ + 4 * g + r > qg) sa[r] = -INFINITY;                         \
        if (k0_ + 16 + 4 * g + r > qg) sb[r] = -INFINITY;                    \
      }                                                                      \
    }                                                                        \
    float pmax = fmaxf(fmaxf(fmaxf(sa[0], sa[1]), fmaxf(sa[2], sa[3])),      \
                       fmaxf(fmaxf(sb[0], sb[1]), fmaxf(sb[2], sb[3])));     \
    if (!__all(pmax <= m + 8.0f)) {                                          \
      float tmax = pmax;                                                     \
      tmax = fmaxf(tmax, __shfl_xor(tmax, 16));                              \
      tmax = fmaxf(tmax, __shfl_xor(tmax, 32));                              \
      const float nm = fmaxf(m, tmax);                                       \
      const float rs = __builtin_amdgcn_exp2f(m - nm);                       \
      l *= rs; o0 *= rs; o1 *= rs; o2 *= rs; o3 *= rs;                       \
      m = nm;                                                                \
    }                                                                        \
    float ps = 0.f;                                                          \
    _Pragma("unroll")                                                        \
    for (int r = 0; r < 4; ++r) {                                            \
      sa[r] = __builtin_amdgcn_exp2f(sa[r] - m); ps += sa[r];                \
      sb[r] = __builtin_amdgcn_exp2f(sb[r] - m); ps += sb[r];                \
    }                                                                        \
    l += ps;                                                                 \
    unsigned pw0, pw1, pw2, pw3;                                             \
    asm("v_cvt_pk_bf16_f32 %0, %1, %2" : "=v"(pw0) : "v"(sa[0]), "v"(sa[1]));\
    asm("v_cvt_pk_bf16_f32 %0, %1, %2" : "=v"(pw1) : "v"(sa[2]), "v"(sa[3]));\
    asm("v_cvt_pk_bf16_f32 %0, %1, %2" : "=v"(pw2) : "v"(sb[0]), "v"(sb[1]));\
    asm("v_cvt_pk_bf16_f32 %0, %1, %2" : "=v"(pw3) : "v"(sb[2]), "v"(sb[3]));\
    const int srcA = q + ((g & 1) << 5);                                     \
    const int srcB = srcA + 16;                                              \
    const unsigned r0a = __shfl((int)pw0, srcA);                             \
    const unsigned r1a = __shfl((int)pw1, srcA);                             \
    const unsigned r2a = __shfl((int)pw2, srcA);                             \
    const unsigned r3a = __shfl((int)pw3, srcA);                             \
    const unsigned r0b = __shfl((int)pw0, srcB);                             \
    const unsigned r1b = __shfl((int)pw1, srcB);                             \
    const unsigned r2b = __shfl((int)pw2, srcB);                             \
    const unsigned r3b = __shfl((int)pw3, srcB);                             \
    union { unsigned u[4]; short8 s; } pf_;                                  \
    const bool hi_ = (g >= 2);                                               \
    pf_.u[0] = hi_ ? r2a : r0a;                                              \
    pf_.u[1] = hi_ ? r3a : r1a;                                              \
    pf_.u[2] = hi_ ? r2b : r0b;                                              \
    pf_.u[3] = hi_ ? r3b : r1b;                                              \
    const short8 Pf = pf_.s;                                                 \
    o0 = __builtin_amdgcn_mfma_f32_16x16x32_bf16(V0, Pf, o0, 0,0,0);         \
    o1 = __builtin_amdgcn_mfma_f32_16x16x32_bf16(V1, Pf, o1, 0,0,0);         \
    o2 = __builtin_amdgcn_mfma_f32_16x16x32_bf16(V2, Pf, o2, 0,0,0);         \
    o3 = __builtin_amdgcn_mfma_f32_16x16x32_bf16(V3, Pf, o3, 0,0,0);         \
  } while (0)

__global__ __launch_bounds__(512) void attn_fwd(
    const unsigned short* __restrict__ qf, const unsigned short* __restrict__ kf,
    const unsigned short* __restrict__ vf, float* __restrict__ out) {
  __shared__ float accS[8][64][17];
  __shared__ float mlS[8][2][16];

  const int tid = threadIdx.x;
  const int w = tid >> 6, lane = tid & 63;
  const int q = lane & 15, g = lane >> 4;

  const int b = blockIdx.x & 7;
  const int p = blockIdx.x >> 3;           // pair 0..63
  const int s1 = 127 - p;
  const int nt0 = (p + 2) >> 1, nt1 = (129 - p) >> 1;   // nt0 + nt1 = 65
  int k = (8 * nt0 + 32) / 65;
  if (k < 1) k = 1;
  if (k > 7) k = 7;

  const bool onS0 = (w < k);
  const int s = onS0 ? p : s1;
  const int nt = onS0 ? nt0 : nt1;
  const int stride = onS0 ? k : (8 - k);

  const int q0 = s * 16;
  const int qg = q0 + q;

  const unsigned short* kfb = kf + (size_t)b * 131072 + (size_t)lane * 8;
  const unsigned short* vfb = vf + (size_t)b * 131072 + (size_t)lane * 8;
  const unsigned short* qfb = qf + (size_t)b * 131072 + (size_t)s * 1024 +
                              (size_t)lane * 8;
  const short8 Qf0 = *(const short8*)&qfb[0];
  const short8 Qf1 = *(const short8*)&qfb[512];

  const f32x4 z = {0.f, 0.f, 0.f, 0.f};

  for (int rep = 0; rep < REPS_A; ++rep) {
    __syncthreads();

    float m = -3.0e38f, l = 0.f;
    f32x4 o0 = z, o1 = z, o2 = z, o3 = z;

    int t = onS0 ? w : (w - k);
    {
      short8 A0, A1, A2, A3, B0, B1, B2, B3;
      const unsigned short* kp0 = kfb + (size_t)t * 2048;
      A0 = *(const short8*)&kp0[0];
      A1 = *(const short8*)&kp0[512];
      A2 = *(const short8*)&kp0[1024];
      A3 = *(const short8*)&kp0[1536];
      for (;;) {
        bool pf = (t + stride) < nt;
        BODY(A0, A1, A2, A3, B0, B1, B2, B3, t, pf);
        if (!pf) break;
        t += stride;
        pf = (t + stride) < nt;
        BODY(B0, B1, B2, B3, A0, A1, A2, A3, t, pf);
        if (!pf) break;
        t += stride;
      }
    }

    float lq = l;
    lq += __shfl_xor(lq, 16);
    lq += __shfl_xor(lq, 32);
    #pragma unroll
    for (int hb = 0; hb < 4; ++hb) {
      const f32x4 a = (hb == 0) ? o0 : (hb == 1) ? o1 : (hb == 2) ? o2 : o3;
      #pragma unroll
      for (int r = 0; r < 4; ++r) accS[w][16 * hb + 4 * g + r][q] = a[r];
    }
    if (g == 0) { mlS[w][0][q] = m; mlS[w][1][q] = lq; }
    __syncthreads();

    const int half = tid >> 8;
    const int sm = half ? s1 : p;
    const int lo = half ? k : 0, hi = half ? 8 : k;
    const int row = tid & 63, qq = (tid >> 6) & 3;
    const long obase = ((long)b * TT + sm * 16) * 64;
    #pragma unroll
    for (int kk = 0; kk < 4; ++kk) {
      const int qv = qq + 4 * kk;
      float M = -INFINITY;
      for (int i = lo; i < hi; ++i) M = fmaxf(M, mlS[i][0][qv]);
      float L = 0.f, acc = 0.f;
      for (int i = lo; i < hi; ++i) {
        const float fi = __builtin_amdgcn_exp2f(mlS[i][0][qv] - M);
        L += fi * mlS[i][1][qv];
        acc += fi * accS[i][row][qv];
      }
      out[obase + (long)qv * 64 + row] = acc / L;
    }
  }
}

extern "C" void kernel_launch(void* const* d_in, const int* in_sizes, int n_in,
                              void* d_out, int out_size, void* d_ws, size_t ws_size,
                              hipStream_t stream) {
  const float* x  = (const float*)d_in[0];
  const float* Wk = (const float*)d_in[1];
  const float* bk = (const float*)d_in[2];
  const float* Wq = (const float*)d_in[3];
  const float* bq = (const float*)d_in[4];
  const float* Wv = (const float*)d_in[5];
  const float* bv = (const float*)d_in[6];
  float* out = (float*)d_out;

  unsigned short* qfb = (unsigned short*)d_ws;             // [B][128][1024]
  unsigned short* kfb = qfb + (size_t)1048576;             // [B][128][1024]
  unsigned short* vfb = kfb + (size_t)1048576;             // [B][64][2048]
  unsigned short* Wf  = vfb + (size_t)1048576;             // [12][32][64][8]

  prep_w<<<dim3(96), 256, 0, stream>>>(Wk, Wq, Wv, Wf);
  qkv_proj<<<dim3(1024), 256, 0, stream>>>(x, bk, bq, bv, Wf, kfb, qfb, vfb);
  attn_fwd<<<dim3(512), 512, 0, stream>>>(qfb, kfb, vfb, out);
}

// Round 18
// 48.712 us; speedup vs baseline: 2.7020x; 2.7020x over previous
//
#include <hip/hip_runtime.h>
#include <hip/hip_bf16.h>
#include <math.h>

#define BB 8
#define TT 2048
#define EE 1024
#define HH 64
// 1/sqrt(64) * log2(e): fold into q so scores are in exp2 domain
#define QSCALE 0.18033688011112042f

typedef __attribute__((ext_vector_type(8))) short short8;
typedef __attribute__((ext_vector_type(4))) float f32x4;
typedef __attribute__((ext_vector_type(4))) unsigned short us4;

__device__ inline unsigned short f2bf(float f) {
  union { __hip_bfloat16 h; unsigned short u; } cv;
  cv.h = __float2bfloat16(f);
  return cv.u;
}

// ---------- prep: fragment-ordered weights --------------------------------
__global__ __launch_bounds__(256) void prep_w(
    const float* __restrict__ Wk, const float* __restrict__ Wq,
    const float* __restrict__ Wv, unsigned short* __restrict__ Wf) {
  const int idx = blockIdx.x * 256 + threadIdx.x;  // 12*32*64 = 24576
  const int lane = idx & 63, ks = (idx >> 6) & 31, t = idx >> 11;
  const int q = lane & 15, g = lane >> 4;
  const int m = t >> 2, h = (t & 3) * 16 + q;
  const float* W = (m == 0) ? Wk : (m == 1) ? Wq : Wv;
  const float sc = (m == 1) ? QSCALE : 1.f;
  const int e0 = ks * 32 + g * 8;
  unsigned short v[8];
  #pragma unroll
  for (int j = 0; j < 8; ++j) v[j] = f2bf(W[(e0 + j) * 64 + h] * sc);
  *(short8*)&Wf[(size_t)idx * 8] = *(short8*)v;
}

// ---------- QKV projection v8: 32 rows/block, chunked dbuf, 6 MFMA/B-load --
// 512 blocks x 256 threads (4 waves). Wave w: N-tiles {3w..3w+2} x 2 M-strips.
// 128-col chunks: stage c+1 (4 float4/thread) overlaps compute of c.
__global__ __launch_bounds__(256) void qkv_proj(
    const float* __restrict__ x,
    const float* __restrict__ bk, const float* __restrict__ bq,
    const float* __restrict__ bv, const unsigned short* __restrict__ Wf,
    unsigned short* __restrict__ kf, unsigned short* __restrict__ qf,
    unsigned short* __restrict__ vf) {
  __shared__ alignas(16) unsigned short xs2[2][32][136];  // 128 cols + pad
  __shared__ alignas(16) unsigned short img[6144];        // K|Q|V images

  const int tid = threadIdx.x;
  const long row0 = (long)blockIdx.x * 32;
  const int w = tid >> 6, lane = tid & 63;
  const int q = lane & 15, g = lane >> 4;

  const float4* xg = (const float4*)&x[row0 * EE];  // 32 rows x 256 float4
  const int rrl = tid >> 5, c4 = tid & 31;          // thread's (row-sub, col4)

  // stage chunk 0 (cols 0..127)
  #pragma unroll
  for (int i = 0; i < 4; ++i) {
    const int rr = i * 8 + rrl;
    const float4 xv = xg[rr * 256 + c4];
    us4 pk = {f2bf(xv.x), f2bf(xv.y), f2bf(xv.z), f2bf(xv.w)};
    *(us4*)&xs2[0][rr][c4 * 4] = pk;
  }
  __syncthreads();

  const f32x4 z = {0.f, 0.f, 0.f, 0.f};
  f32x4 acc00 = z, acc01 = z, acc02 = z;   // M-strip 0 x tiles {3w,3w+1,3w+2}
  f32x4 acc10 = z, acc11 = z, acc12 = z;   // M-strip 1
  const unsigned short* wf0 = &Wf[(size_t)(3 * w) * 16384 + (size_t)lane * 8];

  #pragma unroll 1
  for (int cc = 0; cc < 8; ++cc) {
    float4 st0, st1, st2, st3;
    if (cc < 7) {  // issue next chunk's loads early; hide HBM under MFMA
      const int cb = (cc + 1) * 32 + c4;
      st0 = xg[(0 * 8 + rrl) * 256 + cb];
      st1 = xg[(1 * 8 + rrl) * 256 + cb];
      st2 = xg[(2 * 8 + rrl) * 256 + cb];
      st3 = xg[(3 * 8 + rrl) * 256 + cb];
    }
    #pragma unroll
    for (int ksl = 0; ksl < 4; ++ksl) {
      const int ks = cc * 4 + ksl;
      const short8 a0 = *(const short8*)&xs2[cc & 1][q][ksl * 32 + g * 8];
      const short8 a1 = *(const short8*)&xs2[cc & 1][16 + q][ksl * 32 + g * 8];
      const short8 b0 = *(const short8*)&wf0[ks * 512];
      const short8 b1 = *(const short8*)&wf0[16384 + ks * 512];
      const short8 b2 = *(const short8*)&wf0[32768 + ks * 512];
      acc00 = __builtin_amdgcn_mfma_f32_16x16x32_bf16(a0, b0, acc00, 0, 0, 0);
      acc10 = __builtin_amdgcn_mfma_f32_16x16x32_bf16(a1, b0, acc10, 0, 0, 0);
      acc01 = __builtin_amdgcn_mfma_f32_16x16x32_bf16(a0, b1, acc01, 0, 0, 0);
      acc11 = __builtin_amdgcn_mfma_f32_16x16x32_bf16(a1, b1, acc11, 0, 0, 0);
      acc02 = __builtin_amdgcn_mfma_f32_16x16x32_bf16(a0, b2, acc02, 0, 0, 0);
      acc12 = __builtin_amdgcn_mfma_f32_16x16x32_bf16(a1, b2, acc12, 0, 0, 0);
    }
    if (cc < 7) {
      const int nb = (cc + 1) & 1;
      us4 p0 = {f2bf(st0.x), f2bf(st0.y), f2bf(st0.z), f2bf(st0.w)};
      us4 p1 = {f2bf(st1.x), f2bf(st1.y), f2bf(st1.z), f2bf(st1.w)};
      us4 p2 = {f2bf(st2.x), f2bf(st2.y), f2bf(st2.z), f2bf(st2.w)};
      us4 p3 = {f2bf(st3.x), f2bf(st3.y), f2bf(st3.z), f2bf(st3.w)};
      *(us4*)&xs2[nb][0 * 8 + rrl][c4 * 4] = p0;
      *(us4*)&xs2[nb][1 * 8 + rrl][c4 * 4] = p1;
      *(us4*)&xs2[nb][2 * 8 + rrl][c4 * 4] = p2;
      *(us4*)&xs2[nb][3 * 8 + rrl][c4 * 4] = p3;
      __syncthreads();
    }
  }

  // epilogue: pack into fragment images, then 3 coalesced stores/thread.
  // kq off16 = (h>>5)*512 + ((h&31)>>3)*128 + tl15*8 + (h&7); img [stp][off16]
  // v  off32 = hb*512 + ((tl&31)>>3)*128 + q*8 + (tl&7)
  #pragma unroll
  for (int i = 0; i < 3; ++i) {
    const int tgl = 3 * w + i;
    const int mm = tgl >> 2, hb = tgl & 3;
    const int h = hb * 16 + q;
    const float bias = (mm == 0) ? bk[h] : (mm == 1) ? bq[h] * QSCALE : bv[h];
    #pragma unroll
    for (int stp = 0; stp < 2; ++stp) {
      const f32x4 a = (stp == 0) ? ((i == 0) ? acc00 : (i == 1) ? acc01 : acc02)
                                 : ((i == 0) ? acc10 : (i == 1) ? acc11 : acc12);
      #pragma unroll
      for (int r = 0; r < 4; ++r) {
        const int tlh = 4 * g + r;
        const unsigned short ov = f2bf(a[r] + bias);
        if (mm == 2) {
          img[4096 + hb * 512 + (stp * 2 + (tlh >> 3)) * 128 + q * 8 +
              (tlh & 7)] = ov;
        } else {
          const int g2 = (h & 31) >> 3;
          img[mm * 2048 + stp * 1024 + (h >> 5) * 512 + g2 * 128 + tlh * 8 +
              (h & 7)] = ov;
        }
      }
    }
  }
  __syncthreads();

  const long bidx = row0 >> 11;
  const int tlg = (int)(row0 & 2047);
  const size_t b16 = (size_t)bidx * 131072 + (size_t)(tlg >> 4) * 1024;
  const size_t b32 = (size_t)bidx * 131072 + (size_t)(tlg >> 5) * 2048;
  *(short8*)&kf[b16 + (size_t)tid * 8] = *(const short8*)&img[tid * 8];
  *(short8*)&qf[b16 + (size_t)tid * 8] = *(const short8*)&img[2048 + tid * 8];
  *(short8*)&vf[b32 + (size_t)tid * 8] = *(const short8*)&img[4096 + tid * 8];
}

// ---------- flash attention (R16 verbatim): paired strips, 16x16 MFMA ------
#define BODY(KC0, KC1, KC2, KC3, KN0, KN1, KN2, KN3, tt, PREF) do {          \
    const unsigned short* vp_ = vfb + (size_t)(tt) * 2048;                   \
    const short8 V0 = *(const short8*)&vp_[0];                               \
    const short8 V1 = *(const short8*)&vp_[512];                             \
    const short8 V2 = *(const short8*)&vp_[1024];                            \
    const short8 V3 = *(const short8*)&vp_[1536];                            \
    if (PREF) {                                                              \
      const unsigned short* kp_ = kfb + (size_t)((tt) + stride) * 2048;      \
      KN0 = *(const short8*)&kp_[0];                                         \
      KN1 = *(const short8*)&kp_[512];                                       \
      KN2 = *(const short8*)&kp_[1024];                                      \
      KN3 = *(const short8*)&kp_[1536];                                      \
    }                                                                        \
    f32x4 sa = __builtin_amdgcn_mfma_f32_16x16x32_bf16(KC0, Qf0, z, 0,0,0);  \
    sa = __builtin_amdgcn_mfma_f32_16x16x32_bf16(KC1, Qf1, sa, 0,0,0);       \
    f32x4 sb = __builtin_amdgcn_mfma_f32_16x16x32_bf16(KC2, Qf0, z, 0,0,0);  \
    sb = __builtin_amdgcn_mfma_f32_16x16x32_bf16(KC3, Qf1, sb, 0,0,0);       \
    const int k0_ = (tt) * 32;                                               \
    if (k0_ + 31 > q0) {                                                     \
      _Pragma("unroll")                                                      \
      for (int r = 0; r < 4; ++r) {                                          \
        if (k0_ + 4 * g + r > qg) sa[r] = -INFINITY;                         \
        if (k0_ + 16 + 4 * g + r > qg) sb[r] = -INFINITY;                    \
      }                                                                      \
    }                                                                        \
    float pmax = fmaxf(fmaxf(fmaxf(sa[0], sa[1]), fmaxf(sa[2], sa[3])),      \
                       fmaxf(fmaxf(sb[0], sb[1]), fmaxf(sb[2], sb[3])));     \
    if (!__all(pmax <= m + 8.0f)) {                                          \
      float tmax = pmax;                                                     \
      tmax = fmaxf(tmax, __shfl_xor(tmax, 16));                              \
      tmax = fmaxf(tmax, __shfl_xor(tmax, 32));                              \
      const float nm = fmaxf(m, tmax);                                       \
      const float rs = __builtin_amdgcn_exp2f(m - nm);                       \
      l *= rs; o0 *= rs; o1 *= rs; o2 *= rs; o3 *= rs;                       \
      m = nm;                                                                \
    }                                                                        \
    float ps = 0.f;                                                          \
    _Pragma("unroll")                                                        \
    for (int r = 0; r < 4; ++r) {                                            \
      sa[r] = __builtin_amdgcn_exp2f(sa[r] - m); ps += sa[r];                \
      sb[r] = __builtin_amdgcn_exp2f(sb[r] - m); ps += sb[r];                \
    }                                                                        \
    l += ps;                                                                 \
    unsigned pw0, pw1, pw2, pw3;                                             \
    asm("v_cvt_pk_bf16_f32 %0, %1, %2" : "=v"(pw0) : "v"(sa[0]), "v"(sa[1]));\
    asm("v_cvt_pk_bf16_f32 %0, %1, %2" : "=v"(pw1) : "v"(sa[2]), "v"(sa[3]));\
    asm("v_cvt_pk_bf16_f32 %0, %1, %2" : "=v"(pw2) : "v"(sb[0]), "v"(sb[1]));\
    asm("v_cvt_pk_bf16_f32 %0, %1, %2" : "=v"(pw3) : "v"(sb[2]), "v"(sb[3]));\
    const int srcA = q + ((g & 1) << 5);                                     \
    const int srcB = srcA + 16;                                              \
    const unsigned r0a = __shfl((int)pw0, srcA);                             \
    const unsigned r1a = __shfl((int)pw1, srcA);                             \
    const unsigned r2a = __shfl((int)pw2, srcA);                             \
    const unsigned r3a = __shfl((int)pw3, srcA);                             \
    const unsigned r0b = __shfl((int)pw0, srcB);                             \
    const unsigned r1b = __shfl((int)pw1, srcB);                             \
    const unsigned r2b = __shfl((int)pw2, srcB);                             \
    const unsigned r3b = __shfl((int)pw3, srcB);                             \
    union { unsigned u[4]; short8 s; } pf_;                                  \
    const bool hi_ = (g >= 2);                                               \
    pf_.u[0] = hi_ ? r2a : r0a;                                              \
    pf_.u[1] = hi_ ? r3a : r1a;                                              \
    pf_.u[2] = hi_ ? r2b : r0b;                                              \
    pf_.u[3] = hi_ ? r3b : r1b;                                              \
    const short8 Pf = pf_.s;                                                 \
    o0 = __builtin_amdgcn_mfma_f32_16x16x32_bf16(V0, Pf, o0, 0,0,0);         \
    o1 = __builtin_amdgcn_mfma_f32_16x16x32_bf16(V1, Pf, o1, 0,0,0);         \
    o2 = __builtin_amdgcn_mfma_f32_16x16x32_bf16(V2, Pf, o2, 0,0,0);         \
    o3 = __builtin_amdgcn_mfma_f32_16x16x32_bf16(V3, Pf, o3, 0,0,0);         \
  } while (0)

__global__ __launch_bounds__(512) void attn_fwd(
    const unsigned short* __restrict__ qf, const unsigned short* __restrict__ kf,
    const unsigned short* __restrict__ vf, float* __restrict__ out) {
  __shared__ float accS[8][64][17];
  __shared__ float mlS[8][2][16];

  const int tid = threadIdx.x;
  const int w = tid >> 6, lane = tid & 63;
  const int q = lane & 15, g = lane >> 4;

  const int b = blockIdx.x & 7;
  const int p = blockIdx.x >> 3;           // pair 0..63
  const int s1 = 127 - p;
  const int nt0 = (p + 2) >> 1, nt1 = (129 - p) >> 1;   // nt0 + nt1 = 65
  int k = (8 * nt0 + 32) / 65;
  if (k < 1) k = 1;
  if (k > 7) k = 7;

  const bool onS0 = (w < k);
  const int s = onS0 ? p : s1;
  const int nt = onS0 ? nt0 : nt1;
  const int stride = onS0 ? k : (8 - k);
  int t = onS0 ? w : (w - k);

  const int q0 = s * 16;
  const int qg = q0 + q;

  const unsigned short* kfb = kf + (size_t)b * 131072 + (size_t)lane * 8;
  const unsigned short* vfb = vf + (size_t)b * 131072 + (size_t)lane * 8;
  const unsigned short* qfb = qf + (size_t)b * 131072 + (size_t)s * 1024 +
                              (size_t)lane * 8;
  const short8 Qf0 = *(const short8*)&qfb[0];
  const short8 Qf1 = *(const short8*)&qfb[512];

  const f32x4 z = {0.f, 0.f, 0.f, 0.f};
  float m = -3.0e38f, l = 0.f;
  f32x4 o0 = z, o1 = z, o2 = z, o3 = z;

  {
    short8 A0, A1, A2, A3, B0, B1, B2, B3;
    const unsigned short* kp0 = kfb + (size_t)t * 2048;
    A0 = *(const short8*)&kp0[0];
    A1 = *(const short8*)&kp0[512];
    A2 = *(const short8*)&kp0[1024];
    A3 = *(const short8*)&kp0[1536];
    for (;;) {
      bool pf = (t + stride) < nt;
      BODY(A0, A1, A2, A3, B0, B1, B2, B3, t, pf);
      if (!pf) break;
      t += stride;
      pf = (t + stride) < nt;
      BODY(B0, B1, B2, B3, A0, A1, A2, A3, t, pf);
      if (!pf) break;
      t += stride;
    }
  }

  // finalize per-wave state: l summed across g (2 shfl, once per kernel)
  float lq = l;
  lq += __shfl_xor(lq, 16);
  lq += __shfl_xor(lq, 32);
  #pragma unroll
  for (int hb = 0; hb < 4; ++hb) {
    const f32x4 a = (hb == 0) ? o0 : (hb == 1) ? o1 : (hb == 2) ? o2 : o3;
    #pragma unroll
    for (int r = 0; r < 4; ++r) accS[w][16 * hb + 4 * g + r][q] = a[r];
  }
  if (g == 0) { mlS[w][0][q] = m; mlS[w][1][q] = lq; }
  __syncthreads();

  // merge: tid<256 -> strip p (slots 0..k-1), tid>=256 -> strip 127-p (k..7)
  const int half = tid >> 8;
  const int sm = half ? s1 : p;
  const int lo = half ? k : 0, hi = half ? 8 : k;
  const int row = tid & 63, qq = (tid >> 6) & 3;
  const long obase = ((long)b * TT + sm * 16) * 64;
  #pragma unroll
  for (int kk = 0; kk < 4; ++kk) {
    const int qv = qq + 4 * kk;
    float M = -INFINITY;
    for (int i = lo; i < hi; ++i) M = fmaxf(M, mlS[i][0][qv]);
    float L = 0.f, acc = 0.f;
    for (int i = lo; i < hi; ++i) {
      const float fi = __builtin_amdgcn_exp2f(mlS[i][0][qv] - M);
      L += fi * mlS[i][1][qv];
      acc += fi * accS[i][row][qv];
    }
    out[obase + (long)qv * 64 + row] = acc / L;
  }
}

extern "C" void kernel_launch(void* const* d_in, const int* in_sizes, int n_in,
                              void* d_out, int out_size, void* d_ws, size_t ws_size,
                              hipStream_t stream) {
  const float* x  = (const float*)d_in[0];
  const float* Wk = (const float*)d_in[1];
  const float* bk = (const float*)d_in[2];
  const float* Wq = (const float*)d_in[3];
  const float* bq = (const float*)d_in[4];
  const float* Wv = (const float*)d_in[5];
  const float* bv = (const float*)d_in[6];
  float* out = (float*)d_out;

  unsigned short* qfb = (unsigned short*)d_ws;             // [B][128][1024]
  unsigned short* kfb = qfb + (size_t)1048576;             // [B][128][1024]
  unsigned short* vfb = kfb + (size_t)1048576;             // [B][64][2048]
  unsigned short* Wf  = vfb + (size_t)1048576;             // [12][32][64][8]

  prep_w<<<dim3(96), 256, 0, stream>>>(Wk, Wq, Wv, Wf);
  qkv_proj<<<dim3(512), 256, 0, stream>>>(x, bk, bq, bv, Wf, kfb, qfb, vfb);
  attn_fwd<<<dim3(512), 512, 0, stream>>>(qfb, kfb, vfb, out);
}